// Round 17
// baseline (35.370 us; speedup 1.0000x reference)
//
#include <hip/hip_runtime.h>
#include <hip/hip_bf16.h>

// R17: single fused kernel. Blocks 0-47 = R13 prep (verbatim); release-
// publish via agent-scope atomic. All blocks: Phase A (unfold, ws-independent,
// overlaps prep) -> acquire-spin on flag -> Phases B/C/epilogue (R14 verbatim).
// Flag zeroed each replay by a tiny hipMemsetAsync node. Deadlock-free by
// dispatch order; cross-XCD visibility via release/acquire AGENT atomics.

#define CKK 288
#define SJ  296   // padded j-stride for u_lds (bf16 elems)

typedef __attribute__((ext_vector_type(8))) short short8;
typedef __attribute__((ext_vector_type(4))) float f32x4;

// ws layout in bf16 elements
#define W2F_OFF 0               // [64 w8][9 kb][64 lane][8] fragment order
#define W1B_OFF 294912          // [32][288] row order
#define B2B_OFF (294912 + 9216) // [32][288] row order
#define FLAG_BYTE 626688        // 4-byte flag after all weight data

// LDS union (bytes): prep lds_f = 32*289*4 = 36992 ; main = 25216
#define SMEM_BYTES 36992
#define U_B   0                 // bf16 [32][SJ] = 18944
#define HH_B  18944             // f32 [32][33]  = 4224
#define T_B   23168             // f32 [32][8]   = 1024
#define O_B   24192             // f32 [8][32]   = 1024

__device__ __forceinline__ short f2bf(float f) {
    __hip_bfloat16 h = __float2bfloat16(f);
    return __builtin_bit_cast(short, h);
}

__global__ __launch_bounds__(256, 4) void dynaconv_fused(
    const float* __restrict__ x,    const float* __restrict__ W1,
    const float* __restrict__ b1,   const float* __restrict__ W2,
    const float* __restrict__ b2,   const float* __restrict__ bias,
    __hip_bfloat16* __restrict__ ws, float* __restrict__ out)
{
    __shared__ __align__(16) char smem[SMEM_BYTES];
    const int t = threadIdx.x;
    unsigned int* flag = (unsigned int*)((char*)ws + FLAG_BYTE);

    // ============ Stage 0 (blocks 0-47): prep, R13 verbatim ============
    if (blockIdx.x < 48) {
        if (blockIdx.x < 32) {
            float* lds_f = (float*)smem;        // [32][289]
            const int o = blockIdx.x;
            #pragma unroll
            for (int k = 0; k < 36; ++k) {
                int idx = k * 256 + t;          // 9216, coalesced read
                int j = idx >> 5, h = idx & 31;
                lds_f[h * 289 + j] = W2[o * 9216 + idx];
            }
            __syncthreads();
            #pragma unroll
            for (int k = 0; k < 5; ++k) {
                int c = k * 256 + t;            // 1152 chunks of 8 bf16
                if (c < 1152) {
                    int nf = c / 576, rem = c - nf * 576;
                    int kb = rem >> 6, l = rem & 63;
                    int h  = nf * 16 + (l & 15);
                    int j0 = kb * 32 + ((l >> 4) << 3);
                    short8 v;
                    #pragma unroll
                    for (int e = 0; e < 8; ++e)
                        v[e] = f2bf(lds_f[h * 289 + j0 + e]);
                    *(short8*)(ws + W2F_OFF + (size_t)(o * 9216) + c * 8) = v;
                }
            }
        } else if (blockIdx.x < 40) {
            int b0 = (blockIdx.x - 32) * 1152;
            #pragma unroll
            for (int k = 0; k < 5; ++k) {
                int c = k * 256 + t;
                if (c < 1152) ws[W1B_OFF + b0 + c] = __float2bfloat16(W1[b0 + c]);
            }
        } else {
            int b0 = (blockIdx.x - 40) * 1152;
            #pragma unroll
            for (int k = 0; k < 5; ++k) {
                int c = k * 256 + t;
                if (c < 1152) ws[B2B_OFF + b0 + c] = __float2bfloat16(b2[b0 + c]);
            }
        }
        __syncthreads();   // all stores drained (vmcnt) before publish; lds_f free
        if (t == 0)
            __hip_atomic_fetch_add(flag, 1u, __ATOMIC_RELEASE,
                                   __HIP_MEMORY_SCOPE_AGENT);
    }

    // ============ Stage 1: main (R14 verbatim, LDS via union) ============
    __hip_bfloat16* u_lds = (__hip_bfloat16*)(smem + U_B);
    float* hh_lds  = (float*)(smem + HH_B);
    float* t_lds   = (float*)(smem + T_B);
    float* o_stage = (float*)(smem + O_B);

    const int w  = t >> 6;   // wave 0..3
    const int l  = t & 63;
    const int lg = l >> 4;
    const int lr = l & 15;

    const int nt = blockIdx.x & 3, mt = blockIdx.x >> 2;
    const int o0 = nt * 8;            // this block's 8 output channels
    const int g0 = mt * 32;           // first global pixel
    const int b  = g0 >> 12;
    const int l0 = g0 & 4095;
    const int y  = l0 >> 6;
    const int wx0 = l0 & 63;

    // ---- Phase A: fused unfold -> u_lds (bf16); ws-independent ----
    #pragma unroll
    for (int k = 0; k < 36; ++k) {
        int idx = k * 256 + t;        // 9216 = 32p * 288j
        int j = idx >> 5, p = idx & 31;
        int c = j / 9, r = j - c * 9;
        int ki = r / 3, kj = r - ki * 3;
        int y2 = y + ki - 1;
        int x2 = wx0 + p + kj - 1;
        float v = 0.f;
        if ((unsigned)y2 < 64u && (unsigned)x2 < 64u)
            v = x[((b * 32 + c) * 64 + y2) * 64 + x2];
        u_lds[p * SJ + j] = __float2bfloat16(v);
    }

    // ---- acquire-spin: all 48 prep parts published ----
    if (t == 0) {
        while (__hip_atomic_load(flag, __ATOMIC_ACQUIRE,
                                 __HIP_MEMORY_SCOPE_AGENT) < 48u)
            __builtin_amdgcn_s_sleep(8);
    }
    __syncthreads();   // also covers Phase A's u_lds writes

    // ---- Phase B: waves 0,1 -> hh (W1); wave 2 -> t (b2, 8 cols) ----
    if (w < 3) {
        const __hip_bfloat16* w1b = ws + W1B_OFF;
        const __hip_bfloat16* b2b = ws + B2B_OFF;
        f32x4 acc0 = {0.f,0.f,0.f,0.f}, acc1 = {0.f,0.f,0.f,0.f};
        #pragma unroll
        for (int kb = 0; kb < 9; ++kb) {
            short8 bf;
            if (w < 2)
                bf = *(const short8*)(w1b + (w * 16 + lr) * CKK + kb * 32 + lg * 8);
            else if (lr < 8)
                bf = *(const short8*)(b2b + (o0 + lr) * CKK + kb * 32 + lg * 8);
            else
                bf = short8{0,0,0,0,0,0,0,0};
            short8 a0 = *(const short8*)(u_lds + lr * SJ + kb * 32 + lg * 8);
            short8 a1 = *(const short8*)(u_lds + (16 + lr) * SJ + kb * 32 + lg * 8);
            acc0 = __builtin_amdgcn_mfma_f32_16x16x32_bf16(a0, bf, acc0, 0, 0, 0);
            acc1 = __builtin_amdgcn_mfma_f32_16x16x32_bf16(a1, bf, acc1, 0, 0, 0);
        }
        if (w < 2) {
            const int col = w * 16 + lr;
            float b1v = b1[col];
            #pragma unroll
            for (int r = 0; r < 4; ++r) {
                hh_lds[(lg * 4 + r) * 33 + col]      = tanhf(acc0[r] + b1v);
                hh_lds[(16 + lg * 4 + r) * 33 + col] = tanhf(acc1[r] + b1v);
            }
        } else if (lr < 8) {
            float bv = bias[o0 + lr];
            #pragma unroll
            for (int r = 0; r < 4; ++r) {
                t_lds[(lg * 4 + r) * 8 + lr]      = acc0[r] + bv;
                t_lds[(16 + lg * 4 + r) * 8 + lr] = acc1[r] + bv;
            }
        }
    }
    __syncthreads();

    // ---- Phase C: S GEMM. wave w owns o = o0 + w*2 .. +1 (4 nf of 16) ----
    f32x4 acc[2][4];
    #pragma unroll
    for (int m = 0; m < 2; ++m)
        #pragma unroll
        for (int nf = 0; nf < 4; ++nf)
            acc[m][nf] = f32x4{0.f, 0.f, 0.f, 0.f};

    {
        const __hip_bfloat16* W2f = ws + W2F_OFF;
        const int ckbase = (o0 * 2 + w * 4) * 9;   // chunk index, nf-stride 9
        short8 bcur[4];
        #pragma unroll
        for (int nf = 0; nf < 4; ++nf)
            bcur[nf] = *(const short8*)(W2f + (size_t)(ckbase + nf * 9) * 512 + l * 8);

        #pragma unroll
        for (int kb = 0; kb < 9; ++kb) {
            short8 a0 = *(const short8*)(u_lds + lr * SJ + kb * 32 + lg * 8);
            short8 a1 = *(const short8*)(u_lds + (16 + lr) * SJ + kb * 32 + lg * 8);
            short8 bnext[4];
            if (kb < 8) {
                #pragma unroll
                for (int nf = 0; nf < 4; ++nf)
                    bnext[nf] = *(const short8*)(W2f + (size_t)(ckbase + nf * 9 + kb + 1) * 512 + l * 8);
            }
            #pragma unroll
            for (int nf = 0; nf < 4; ++nf) {
                acc[0][nf] = __builtin_amdgcn_mfma_f32_16x16x32_bf16(a0, bcur[nf], acc[0][nf], 0, 0, 0);
                acc[1][nf] = __builtin_amdgcn_mfma_f32_16x16x32_bf16(a1, bcur[nf], acc[1][nf], 0, 0, 0);
            }
            if (kb < 8) {
                #pragma unroll
                for (int nf = 0; nf < 4; ++nf)
                    bcur[nf] = bnext[nf];
            }
        }
    }

    // ---- Epilogue: out[p,o] = sum_h hh[p,h]*S[p,o,h] ----
    #pragma unroll
    for (int ol = 0; ol < 2; ++ol) {
        const int o_loc = w * 2 + ol;
        #pragma unroll
        for (int m = 0; m < 2; ++m) {
            #pragma unroll
            for (int r = 0; r < 4; ++r) {
                const int p = m * 16 + lg * 4 + r;
                float v = hh_lds[p * 33 + lr]      * acc[m][ol * 2][r]
                        + hh_lds[p * 33 + 16 + lr] * acc[m][ol * 2 + 1][r];
                v += __shfl_xor(v, 1);
                v += __shfl_xor(v, 2);
                v += __shfl_xor(v, 4);
                v += __shfl_xor(v, 8);
                if (lr == 0) o_stage[o_loc * 32 + p] = v;
            }
        }
    }
    __syncthreads();

    // ---- Store: 8 o x 32 px, coalesced 128B rows ----
    {
        int o_l = t >> 5, p = t & 31;
        float val = o_stage[o_l * 32 + p] + t_lds[p * 8 + o_l];
        out[((size_t)(b * 32 + o0 + o_l)) * 4096 + l0 + p] = val;
    }
}

extern "C" void kernel_launch(void* const* d_in, const int* in_sizes, int n_in,
                              void* d_out, int out_size, void* d_ws, size_t ws_size,
                              hipStream_t stream) {
    const float* x    = (const float*)d_in[0];
    const float* W1   = (const float*)d_in[1];
    const float* b1   = (const float*)d_in[2];
    const float* W2   = (const float*)d_in[3];
    const float* b2   = (const float*)d_in[4];
    const float* bias = (const float*)d_in[5];
    float* out = (float*)d_out;
    __hip_bfloat16* ws = (__hip_bfloat16*)d_ws;

    hipMemsetAsync((char*)d_ws + FLAG_BYTE, 0, 4, stream);
    dynaconv_fused<<<1024, 256, 0, stream>>>(x, W1, b1, W2, b2, bias, ws, out);
}

// Round 19
// 31.154 us; speedup vs baseline: 1.1353x; 1.1353x over previous
//
#include <hip/hip_runtime.h>
#include <hip/hip_bf16.h>

// R19 = R14 verbatim (best passing configuration, 30.9 us).
// prep: LDS-staged W2 transpose (coalesced both sides) + W1/b2 copies.
// main: grid 1024 = 256 mt(32px) x 4 nt(8 o), 256 thr, 4 blk/CU;
//       Phase A unfold -> u_lds; Phase B hh/t via MFMA; Phase C S-GEMM with
//       B-fragment streaming (2-deep) from W2f; shfl h-reduce epilogue.

#define CKK 288
#define SJ  296   // padded j-stride for u_lds (bf16 elems)

typedef __attribute__((ext_vector_type(8))) short short8;
typedef __attribute__((ext_vector_type(4))) float f32x4;

// ws layout in bf16 elements
#define W2F_OFF 0               // [64 w8][9 kb][64 lane][8] fragment order
#define W1B_OFF 294912          // [32][288] row order
#define B2B_OFF (294912 + 9216) // [32][288] row order

__device__ __forceinline__ short f2bf(float f) {
    __hip_bfloat16 h = __float2bfloat16(f);
    return __builtin_bit_cast(short, h);
}

__global__ __launch_bounds__(256) void prep_kernel(
    const float* __restrict__ W1, const float* __restrict__ W2,
    const float* __restrict__ b2, __hip_bfloat16* __restrict__ ws)
{
    const int t = threadIdx.x;
    if (blockIdx.x < 32) {
        // W2 slice o=bid -> LDS[h][j] (289-pad) -> W2f, coalesced both sides
        __shared__ float lds_f[32 * 289];
        const int o = blockIdx.x;
        #pragma unroll
        for (int k = 0; k < 36; ++k) {
            int idx = k * 256 + t;          // 9216, coalesced read
            int j = idx >> 5, h = idx & 31;
            lds_f[h * 289 + j] = W2[o * 9216 + idx];
        }
        __syncthreads();
        #pragma unroll
        for (int k = 0; k < 5; ++k) {
            int c = k * 256 + t;            // 1152 chunks of 8 bf16
            if (c < 1152) {
                int nf = c / 576, rem = c - nf * 576;
                int kb = rem >> 6, l = rem & 63;
                int h  = nf * 16 + (l & 15);
                int j0 = kb * 32 + ((l >> 4) << 3);
                short8 v;
                #pragma unroll
                for (int e = 0; e < 8; ++e)
                    v[e] = f2bf(lds_f[h * 289 + j0 + e]);
                *(short8*)(ws + W2F_OFF + (size_t)(o * 9216) + c * 8) = v;
            }
        }
    } else if (blockIdx.x < 40) {
        int b0 = (blockIdx.x - 32) * 1152;
        #pragma unroll
        for (int k = 0; k < 5; ++k) {
            int c = k * 256 + t;
            if (c < 1152) ws[W1B_OFF + b0 + c] = __float2bfloat16(W1[b0 + c]);
        }
    } else if (blockIdx.x < 48) {
        int b0 = (blockIdx.x - 40) * 1152;
        #pragma unroll
        for (int k = 0; k < 5; ++k) {
            int c = k * 256 + t;
            if (c < 1152) ws[B2B_OFF + b0 + c] = __float2bfloat16(b2[b0 + c]);
        }
    }
}

__global__ __launch_bounds__(256, 4) void dynaconv_main(
    const float* __restrict__ x,     // [2,32,64,64]
    const float* __restrict__ b1,    // [32]
    const float* __restrict__ bias,  // [32]
    const __hip_bfloat16* __restrict__ ws,
    float* __restrict__ out)         // [2,32,4096]
{
    __shared__ __hip_bfloat16 u_lds[32 * SJ];  // [p][j]
    __shared__ float hh_lds[32 * 33];          // [p][h]
    __shared__ float t_lds[32 * 8];            // [p][o_local] (t+bias)
    __shared__ float o_stage[8][32];           // [o_local][p]

    const int t  = threadIdx.x;
    const int w  = t >> 6;   // wave 0..3
    const int l  = t & 63;
    const int lg = l >> 4;
    const int lr = l & 15;

    const int nt = blockIdx.x & 3, mt = blockIdx.x >> 2;
    const int o0 = nt * 8;            // this block's 8 output channels
    const int g0 = mt * 32;           // first global pixel
    const int b  = g0 >> 12;
    const int l0 = g0 & 4095;
    const int y  = l0 >> 6;
    const int wx0 = l0 & 63;

    // ---- Phase A: fused unfold -> u_lds (bf16) ----
    #pragma unroll
    for (int k = 0; k < 36; ++k) {
        int idx = k * 256 + t;        // 9216 = 32p * 288j
        int j = idx >> 5, p = idx & 31;
        int c = j / 9, r = j - c * 9;
        int ki = r / 3, kj = r - ki * 3;
        int y2 = y + ki - 1;
        int x2 = wx0 + p + kj - 1;
        float v = 0.f;
        if ((unsigned)y2 < 64u && (unsigned)x2 < 64u)
            v = x[((b * 32 + c) * 64 + y2) * 64 + x2];
        u_lds[p * SJ + j] = __float2bfloat16(v);
    }
    __syncthreads();

    // ---- Phase B: waves 0,1 -> hh (W1); wave 2 -> t (b2, 8 cols) ----
    if (w < 3) {
        const __hip_bfloat16* w1b = ws + W1B_OFF;
        const __hip_bfloat16* b2b = ws + B2B_OFF;
        f32x4 acc0 = {0.f,0.f,0.f,0.f}, acc1 = {0.f,0.f,0.f,0.f};
        #pragma unroll
        for (int kb = 0; kb < 9; ++kb) {
            short8 bf;
            if (w < 2)
                bf = *(const short8*)(w1b + (w * 16 + lr) * CKK + kb * 32 + lg * 8);
            else if (lr < 8)
                bf = *(const short8*)(b2b + (o0 + lr) * CKK + kb * 32 + lg * 8);
            else
                bf = short8{0,0,0,0,0,0,0,0};
            short8 a0 = *(const short8*)(u_lds + lr * SJ + kb * 32 + lg * 8);
            short8 a1 = *(const short8*)(u_lds + (16 + lr) * SJ + kb * 32 + lg * 8);
            acc0 = __builtin_amdgcn_mfma_f32_16x16x32_bf16(a0, bf, acc0, 0, 0, 0);
            acc1 = __builtin_amdgcn_mfma_f32_16x16x32_bf16(a1, bf, acc1, 0, 0, 0);
        }
        if (w < 2) {
            const int col = w * 16 + lr;
            float b1v = b1[col];
            #pragma unroll
            for (int r = 0; r < 4; ++r) {
                hh_lds[(lg * 4 + r) * 33 + col]      = tanhf(acc0[r] + b1v);
                hh_lds[(16 + lg * 4 + r) * 33 + col] = tanhf(acc1[r] + b1v);
            }
        } else if (lr < 8) {
            float bv = bias[o0 + lr];
            #pragma unroll
            for (int r = 0; r < 4; ++r) {
                t_lds[(lg * 4 + r) * 8 + lr]      = acc0[r] + bv;
                t_lds[(16 + lg * 4 + r) * 8 + lr] = acc1[r] + bv;
            }
        }
    }
    __syncthreads();

    // ---- Phase C: S GEMM. wave w owns o = o0 + w*2 .. +1 (4 nf of 16) ----
    f32x4 acc[2][4];
    #pragma unroll
    for (int m = 0; m < 2; ++m)
        #pragma unroll
        for (int nf = 0; nf < 4; ++nf)
            acc[m][nf] = f32x4{0.f, 0.f, 0.f, 0.f};

    {
        const __hip_bfloat16* W2f = ws + W2F_OFF;
        const int ckbase = (o0 * 2 + w * 4) * 9;   // chunk index, nf-stride 9
        short8 bcur[4];
        #pragma unroll
        for (int nf = 0; nf < 4; ++nf)
            bcur[nf] = *(const short8*)(W2f + (size_t)(ckbase + nf * 9) * 512 + l * 8);

        #pragma unroll
        for (int kb = 0; kb < 9; ++kb) {
            short8 a0 = *(const short8*)(u_lds + lr * SJ + kb * 32 + lg * 8);
            short8 a1 = *(const short8*)(u_lds + (16 + lr) * SJ + kb * 32 + lg * 8);
            short8 bnext[4];
            if (kb < 8) {
                #pragma unroll
                for (int nf = 0; nf < 4; ++nf)
                    bnext[nf] = *(const short8*)(W2f + (size_t)(ckbase + nf * 9 + kb + 1) * 512 + l * 8);
            }
            #pragma unroll
            for (int nf = 0; nf < 4; ++nf) {
                acc[0][nf] = __builtin_amdgcn_mfma_f32_16x16x32_bf16(a0, bcur[nf], acc[0][nf], 0, 0, 0);
                acc[1][nf] = __builtin_amdgcn_mfma_f32_16x16x32_bf16(a1, bcur[nf], acc[1][nf], 0, 0, 0);
            }
            if (kb < 8) {
                #pragma unroll
                for (int nf = 0; nf < 4; ++nf)
                    bcur[nf] = bnext[nf];
            }
        }
    }

    // ---- Epilogue: out[p,o] = sum_h hh[p,h]*S[p,o,h] ----
    #pragma unroll
    for (int ol = 0; ol < 2; ++ol) {
        const int o_loc = w * 2 + ol;
        #pragma unroll
        for (int m = 0; m < 2; ++m) {
            #pragma unroll
            for (int r = 0; r < 4; ++r) {
                const int p = m * 16 + lg * 4 + r;
                float v = hh_lds[p * 33 + lr]      * acc[m][ol * 2][r]
                        + hh_lds[p * 33 + 16 + lr] * acc[m][ol * 2 + 1][r];
                v += __shfl_xor(v, 1);
                v += __shfl_xor(v, 2);
                v += __shfl_xor(v, 4);
                v += __shfl_xor(v, 8);
                if (lr == 0) o_stage[o_loc][p] = v;
            }
        }
    }
    __syncthreads();

    // ---- Store: 8 o x 32 px, coalesced 128B rows ----
    {
        int o_l = t >> 5, p = t & 31;
        float val = o_stage[o_l][p] + t_lds[p * 8 + o_l];
        out[((size_t)(b * 32 + o0 + o_l)) * 4096 + l0 + p] = val;
    }
}

extern "C" void kernel_launch(void* const* d_in, const int* in_sizes, int n_in,
                              void* d_out, int out_size, void* d_ws, size_t ws_size,
                              hipStream_t stream) {
    const float* x    = (const float*)d_in[0];
    const float* W1   = (const float*)d_in[1];
    const float* b1   = (const float*)d_in[2];
    const float* W2   = (const float*)d_in[3];
    const float* b2   = (const float*)d_in[4];
    const float* bias = (const float*)d_in[5];
    float* out = (float*)d_out;
    __hip_bfloat16* ws = (__hip_bfloat16*)d_ws;

    prep_kernel<<<48, 256, 0, stream>>>(W1, W2, b2, ws);
    dynaconv_main<<<1024, 256, 0, stream>>>(x, b1, bias, ws, out);
}